// Round 1
// baseline (197.076 us; speedup 1.0000x reference)
//
#include <hip/hip_runtime.h>
#include <math.h>

typedef __attribute__((ext_vector_type(8))) short short8;
typedef __attribute__((ext_vector_type(4))) short short4v;
typedef __attribute__((ext_vector_type(4))) float f32x4;

#define S_LEN 2048
#define D_HEAD 64

static __device__ __forceinline__ unsigned short f2bf(float x) {
    union { float f; unsigned u; } a; a.f = x;
    unsigned r = a.u + (0x7fffu + ((a.u >> 16) & 1u));   // RNE
    return (unsigned short)(r >> 16);
}
static __device__ __forceinline__ float bf2f(unsigned short h) {
    union { unsigned u; float f; } a; a.u = ((unsigned)h) << 16;
    return a.f;
}

// ---- prep: T5 relative-position bias baked to [h][delta+2047], pre-scaled by 1/8 ----
__global__ void prep_bias(const float* __restrict__ table, float* __restrict__ bias_d) {
    int idx = blockIdx.x * blockDim.x + threadIdx.x;   // 0..4095 (4095 = unused pad)
    if (idx >= 4096) return;
    int delta = idx - 2047;                 // k - q
    int bpos = (delta > 0) ? 16 : 0;
    int ad = delta < 0 ? -delta : delta;
    int rel;
    if (ad < 8) {
        rel = bpos + ad;
    } else {
        float rp = (float)ad;
        int lg = 8 + (int)(logf(rp / 8.0f) / 2.772588722239781f * 8.0f);  // log(16)
        if (lg > 15) lg = 15;
        rel = bpos + lg;
    }
    #pragma unroll
    for (int h = 0; h < 4; ++h)
        bias_d[h * 4096 + idx] = 0.125f * table[rel * 4 + h];
}

// ---- prep: V [bh][k][d] fp32  ->  V^T hi/lo bf16 [bh][d][k] ----
__global__ void prep_vt(const float* __restrict__ V, unsigned short* __restrict__ vthi,
                        unsigned short* __restrict__ vtlo) {
    __shared__ float tile[64][65];
    const int bh = blockIdx.y;
    const int k0 = blockIdx.x * 64;
    const int t = threadIdx.x;
    {
        int r = t >> 2, c0 = (t & 3) * 16;
        const float* src = V + ((size_t)bh * S_LEN + k0 + r) * D_HEAD + c0;
        #pragma unroll
        for (int i = 0; i < 16; i += 4) {
            f32x4 v = *(const f32x4*)(src + i);
            tile[r][c0 + i + 0] = v[0];
            tile[r][c0 + i + 1] = v[1];
            tile[r][c0 + i + 2] = v[2];
            tile[r][c0 + i + 3] = v[3];
        }
    }
    __syncthreads();
    {
        int d = t >> 2, kc = (t & 3) * 16;
        size_t ob = ((size_t)bh * D_HEAD + d) * S_LEN + k0 + kc;
        #pragma unroll
        for (int half = 0; half < 2; ++half) {
            short8 hv, lv;
            #pragma unroll
            for (int i = 0; i < 8; ++i) {
                float x = tile[kc + half * 8 + i][d];
                unsigned short hb = f2bf(x);
                hv[i] = (short)hb;
                lv[i] = (short)f2bf(x - bf2f(hb));
            }
            *(short8*)(vthi + ob + half * 8) = hv;
            *(short8*)(vtlo + ob + half * 8) = lv;
        }
    }
}

// ---- main: two-pass fused attention, 64 q-rows/block, 8 waves (4 wq x 2 wk) ----
__launch_bounds__(512)
__global__ void attn_main(const float* __restrict__ Q, const float* __restrict__ K,
                          const int* __restrict__ mask, const float* __restrict__ bias_d,
                          const unsigned short* __restrict__ vthi,
                          const unsigned short* __restrict__ vtlo,
                          float* __restrict__ outp, float* __restrict__ p_out) {
    __shared__ __align__(16) char smem[54784];
    unsigned short (*khi)[72] = (unsigned short (*)[72])(smem + 0);      // also Q-hi staging
    unsigned short (*klo)[72] = (unsigned short (*)[72])(smem + 9216);   // also Q-lo staging
    unsigned short (*vth)[72] = (unsigned short (*)[72])(smem + 18432);
    unsigned short (*vtl)[72] = (unsigned short (*)[72])(smem + 27648);
    unsigned short* pball = (unsigned short*)(smem + 36864);             // 16 KB: p hi/lo per wave; later out-reduce
    float* stats = (float*)(smem + 53248);
    float* mfin  = (float*)(smem + 54272);
    float* rlfin = (float*)(smem + 54528);

    const int tid = threadIdx.x;
    const int w = tid >> 6, l = tid & 63;
    const int wq = w & 3, wk = w >> 2;
    const int g = l >> 4, lq = l & 15;
    const int bh = blockIdx.y, b = bh >> 2, h = bh & 3;
    const int q0 = blockIdx.x * 64;

    const float* Qp = Q + (size_t)bh * S_LEN * D_HEAD;
    const float* Kp = K + (size_t)bh * S_LEN * D_HEAD;
    const int* mp = mask + b * S_LEN;
    const unsigned short* vhp = vthi + (size_t)bh * D_HEAD * S_LEN;
    const unsigned short* vlp = vtlo + (size_t)bh * D_HEAD * S_LEN;

    const int sr = tid >> 3, sc = (tid & 7) * 8;   // staging row / col(8-wide)

    // ---- stage Q tile -> bf16 hi/lo (into khi/klo region, consumed once) ----
    {
        const float* src = Qp + (size_t)(q0 + sr) * D_HEAD + sc;
        f32x4 a = *(const f32x4*)src;
        f32x4 c = *(const f32x4*)(src + 4);
        float xs[8] = {a[0], a[1], a[2], a[3], c[0], c[1], c[2], c[3]};
        short8 hv, lv;
        #pragma unroll
        for (int i = 0; i < 8; ++i) {
            unsigned short hb = f2bf(xs[i]);
            hv[i] = (short)hb;
            lv[i] = (short)f2bf(xs[i] - bf2f(hb));
        }
        *(short8*)&khi[sr][sc] = hv;
        *(short8*)&klo[sr][sc] = lv;
    }
    __syncthreads();
    short8 qfh[2], qfl[2];   // B-operand frags: col = q(lane&15), k-dim = d
    #pragma unroll
    for (int c = 0; c < 2; ++c) {
        qfh[c] = *(const short8*)&khi[16 * wq + lq][32 * c + 8 * g];
        qfl[c] = *(const short8*)&klo[16 * wq + lq][32 * c + 8 * g];
    }
    const int qq = q0 + 16 * wq + lq;               // this lane's q row (QK/softmax phase)
    const float* bprow = bias_d + h * 4096 + 2047 - qq;  // bias at [k - q + 2047]

    // ================= PASS 1: row stats (plain bf16 QK^T) =================
    float m = -INFINITY, lsum = 0.0f;
    for (int it = 0; it < 32; ++it) {
        const int kb = it * 64;
        __syncthreads();
        {
            const float* src = Kp + (size_t)(kb + sr) * D_HEAD + sc;
            f32x4 a = *(const f32x4*)src;
            f32x4 c = *(const f32x4*)(src + 4);
            float xs[8] = {a[0], a[1], a[2], a[3], c[0], c[1], c[2], c[3]};
            short8 hv;
            #pragma unroll
            for (int i = 0; i < 8; ++i) hv[i] = (short)f2bf(xs[i]);
            *(short8*)&khi[sr][sc] = hv;
        }
        __syncthreads();
        #pragma unroll
        for (int t2 = 0; t2 < 2; ++t2) {
            const int krow = 32 * wk + 16 * t2 + lq;
            f32x4 acc = {0.f, 0.f, 0.f, 0.f};
            #pragma unroll
            for (int c = 0; c < 2; ++c) {
                short8 af = *(const short8*)&khi[krow][32 * c + 8 * g];
                acc = __builtin_amdgcn_mfma_f32_16x16x32_bf16(af, qfh[c], acc, 0, 0, 0);
            }
            const int k0 = kb + 32 * wk + 16 * t2 + 4 * g;
            const int4 mv = *(const int4*)(mp + k0);
            float sv0 = mv.x ? acc[0] * 0.125f + bprow[k0 + 0] : -1e9f;
            float sv1 = mv.y ? acc[1] * 0.125f + bprow[k0 + 1] : -1e9f;
            float sv2 = mv.z ? acc[2] * 0.125f + bprow[k0 + 2] : -1e9f;
            float sv3 = mv.w ? acc[3] * 0.125f + bprow[k0 + 3] : -1e9f;
            float tmax = fmaxf(fmaxf(sv0, sv1), fmaxf(sv2, sv3));
            float mn = fmaxf(m, tmax);
            lsum = lsum * __expf(m - mn) + __expf(sv0 - mn) + __expf(sv1 - mn)
                 + __expf(sv2 - mn) + __expf(sv3 - mn);
            m = mn;
        }
    }
    // combine the 4 k-slices held across lane groups (lanes ^16, ^32)
    #pragma unroll
    for (int off = 16; off <= 32; off <<= 1) {
        float mo = __shfl_xor(m, off);
        float lo2 = __shfl_xor(lsum, off);
        float mn = fmaxf(m, mo);
        lsum = lsum * __expf(m - mn) + lo2 * __expf(mo - mn);
        m = mn;
    }
    if (g == 0) {
        stats[(wk * 2 + 0) * 64 + 16 * wq + lq] = m;
        stats[(wk * 2 + 1) * 64 + 16 * wq + lq] = lsum;
    }
    __syncthreads();
    if (tid < 64) {
        float m0 = stats[tid], l0 = stats[64 + tid];
        float m1 = stats[128 + tid], l1 = stats[192 + tid];
        float M = fmaxf(m0, m1);
        float L = l0 * __expf(m0 - M) + l1 * __expf(m1 - M);
        mfin[tid] = M;
        rlfin[tid] = 1.0f / L;
    }
    __syncthreads();
    const float mq = mfin[16 * wq + lq];
    const float rlq = rlfin[16 * wq + lq];

    // ================= PASS 2: exact scores (bf16x3), write p, accumulate PV =================
    f32x4 acco[4] = {{0.f,0.f,0.f,0.f},{0.f,0.f,0.f,0.f},{0.f,0.f,0.f,0.f},{0.f,0.f,0.f,0.f}};
    unsigned short* pbh = pball + (w << 9);
    unsigned short* pbl = pball + 4096 + (w << 9);
    float* po_row = p_out + (size_t)bh * S_LEN * S_LEN + (size_t)qq * S_LEN;

    for (int it = 0; it < 32; ++it) {
        const int kb = it * 64;
        __syncthreads();
        {   // stage K hi/lo + V^T hi/lo tiles
            const float* src = Kp + (size_t)(kb + sr) * D_HEAD + sc;
            f32x4 a = *(const f32x4*)src;
            f32x4 c = *(const f32x4*)(src + 4);
            float xs[8] = {a[0], a[1], a[2], a[3], c[0], c[1], c[2], c[3]};
            short8 hv, lv;
            #pragma unroll
            for (int i = 0; i < 8; ++i) {
                unsigned short hb = f2bf(xs[i]);
                hv[i] = (short)hb;
                lv[i] = (short)f2bf(xs[i] - bf2f(hb));
            }
            *(short8*)&khi[sr][sc] = hv;
            *(short8*)&klo[sr][sc] = lv;
            *(short8*)&vth[sr][sc] = *(const short8*)(vhp + (size_t)sr * S_LEN + kb + sc);
            *(short8*)&vtl[sr][sc] = *(const short8*)(vlp + (size_t)sr * S_LEN + kb + sc);
        }
        __syncthreads();
        #pragma unroll
        for (int t2 = 0; t2 < 2; ++t2) {
            const int krow = 32 * wk + 16 * t2 + lq;
            f32x4 acc = {0.f, 0.f, 0.f, 0.f};
            #pragma unroll
            for (int c = 0; c < 2; ++c) {
                short8 ah = *(const short8*)&khi[krow][32 * c + 8 * g];
                short8 al = *(const short8*)&klo[krow][32 * c + 8 * g];
                acc = __builtin_amdgcn_mfma_f32_16x16x32_bf16(ah, qfh[c], acc, 0, 0, 0);
                acc = __builtin_amdgcn_mfma_f32_16x16x32_bf16(al, qfh[c], acc, 0, 0, 0);
                acc = __builtin_amdgcn_mfma_f32_16x16x32_bf16(ah, qfl[c], acc, 0, 0, 0);
            }
            const int k0 = kb + 32 * wk + 16 * t2 + 4 * g;
            const int4 mv = *(const int4*)(mp + k0);
            float s0 = mv.x ? acc[0] * 0.125f + bprow[k0 + 0] : -1e9f;
            float s1 = mv.y ? acc[1] * 0.125f + bprow[k0 + 1] : -1e9f;
            float s2 = mv.z ? acc[2] * 0.125f + bprow[k0 + 2] : -1e9f;
            float s3 = mv.w ? acc[3] * 0.125f + bprow[k0 + 3] : -1e9f;
            float p0 = __expf(s0 - mq) * rlq;
            float p1 = __expf(s1 - mq) * rlq;
            float p2 = __expf(s2 - mq) * rlq;
            float p3 = __expf(s3 - mq) * rlq;
            f32x4 pw = {p0, p1, p2, p3};
            *(f32x4*)(po_row + k0) = pw;                   // final normalized p -> global
            short4v ph4, pl4;
            float pv[4] = {p0, p1, p2, p3};
            #pragma unroll
            for (int r = 0; r < 4; ++r) {
                unsigned short hb = f2bf(pv[r]);
                ph4[r] = (short)hb;
                pl4[r] = (short)f2bf(pv[r] - bf2f(hb));
            }
            *(short4v*)(pbh + (lq << 5) + 16 * t2 + 4 * g) = ph4;
            *(short4v*)(pbl + (lq << 5) + 16 * t2 + 4 * g) = pl4;
        }
        // PV: A = P[16q x 32k] (own wave's LDS buffer), B = V^T[d][k]
        const short8 pfh = *(const short8*)(pbh + (lq << 5) + 8 * g);
        const short8 pfl = *(const short8*)(pbl + (lq << 5) + 8 * g);
        #pragma unroll
        for (int n = 0; n < 4; ++n) {
            const short8 bhf = *(const short8*)&vth[16 * n + lq][32 * wk + 8 * g];
            const short8 blf = *(const short8*)&vtl[16 * n + lq][32 * wk + 8 * g];
            acco[n] = __builtin_amdgcn_mfma_f32_16x16x32_bf16(pfh, bhf, acco[n], 0, 0, 0);
            acco[n] = __builtin_amdgcn_mfma_f32_16x16x32_bf16(pfl, bhf, acco[n], 0, 0, 0);
            acco[n] = __builtin_amdgcn_mfma_f32_16x16x32_bf16(pfh, blf, acco[n], 0, 0, 0);
        }
    }

    // ---- reduce the two k-half waves and store out ----
    __syncthreads();
    float* ored = (float*)pball;    // [4 wq][16 q][64 d]
    if (wk == 1) {
        #pragma unroll
        for (int n = 0; n < 4; ++n)
            #pragma unroll
            for (int r = 0; r < 4; ++r)
                ored[(wq * 16 + 4 * g + r) * 64 + 16 * n + lq] = acco[n][r];
    }
    __syncthreads();
    if (wk == 0) {
        #pragma unroll
        for (int n = 0; n < 4; ++n) {
            #pragma unroll
            for (int r = 0; r < 4; ++r) {
                float v = acco[n][r] + ored[(wq * 16 + 4 * g + r) * 64 + 16 * n + lq];
                outp[((size_t)bh * S_LEN + q0 + 16 * wq + 4 * g + r) * D_HEAD + 16 * n + lq] = v;
            }
        }
    }
}

extern "C" void kernel_launch(void* const* d_in, const int* in_sizes, int n_in,
                              void* d_out, int out_size, void* d_ws, size_t ws_size,
                              hipStream_t stream) {
    const float* Q = (const float*)d_in[0];
    const float* K = (const float*)d_in[1];
    const float* V = (const float*)d_in[2];
    const int* mask = (const int*)d_in[3];
    const float* table = (const float*)d_in[4];

    float* outp = (float*)d_out;
    float* p_out = outp + (size_t)4 * 4 * 2048 * 64;   // out first, then p_attn

    float* bias_d = (float*)d_ws;                                   // 64 KB
    unsigned short* vthi = (unsigned short*)((char*)d_ws + 65536);  // 4 MB
    unsigned short* vtlo = vthi + (size_t)16 * 64 * 2048;           // 4 MB

    prep_bias<<<16, 256, 0, stream>>>(table, bias_d);
    prep_vt<<<dim3(32, 16), 256, 0, stream>>>(V, vthi, vtlo);
    attn_main<<<dim3(32, 16), 512, 0, stream>>>(Q, K, mask, bias_d, vthi, vtlo, outp, p_out);
}

// Round 2
// 173.018 us; speedup vs baseline: 1.1390x; 1.1390x over previous
//
#include <hip/hip_runtime.h>
#include <math.h>

typedef __attribute__((ext_vector_type(8))) short short8;
typedef __attribute__((ext_vector_type(4))) short short4v;
typedef __attribute__((ext_vector_type(4))) float f32x4;
typedef unsigned short u16;

#define S_LEN 2048
#define D_HEAD 64

static __device__ __forceinline__ u16 f2bf(float x) {
    union { float f; unsigned u; } a; a.f = x;
    unsigned r = a.u + (0x7fffu + ((a.u >> 16) & 1u));   // RNE
    return (u16)(r >> 16);
}
static __device__ __forceinline__ float bf2f(u16 h) {
    union { unsigned u; float f; } a; a.u = ((unsigned)h) << 16;
    return a.f;
}

static __device__ __forceinline__ void gl_lds16(const void* g, void* l) {
    __builtin_amdgcn_global_load_lds(
        (const __attribute__((address_space(1))) unsigned int*)g,
        (__attribute__((address_space(3))) unsigned int*)l, 16, 0, 0);
}

// ---- prep: T5 relative-position bias baked to [h][delta+2047], pre-scaled by 1/8 ----
__global__ void prep_bias(const float* __restrict__ table, float* __restrict__ bias_d) {
    int idx = blockIdx.x * blockDim.x + threadIdx.x;   // 0..4095
    if (idx >= 4096) return;
    int delta = idx - 2047;                 // k - q
    int bpos = (delta > 0) ? 16 : 0;
    int ad = delta < 0 ? -delta : delta;
    int rel;
    if (ad < 8) {
        rel = bpos + ad;
    } else {
        float rp = (float)ad;
        int lg = 8 + (int)(logf(rp / 8.0f) / 2.772588722239781f * 8.0f);  // log(16)
        if (lg > 15) lg = 15;
        rel = bpos + lg;
    }
    #pragma unroll
    for (int h = 0; h < 4; ++h)
        bias_d[h * 4096 + idx] = 0.125f * table[rel * 4 + h];
}

// ---- prep: elementwise fp32 -> bf16 hi/lo split (for K) ----
__global__ void prep_split(const float* __restrict__ src, u16* __restrict__ hi,
                           u16* __restrict__ lo) {
    size_t i8 = ((size_t)blockIdx.x * 256 + threadIdx.x) * 8;
    f32x4 a = *(const f32x4*)(src + i8);
    f32x4 b = *(const f32x4*)(src + i8 + 4);
    float xs[8] = {a[0], a[1], a[2], a[3], b[0], b[1], b[2], b[3]};
    short8 hv, lv;
    #pragma unroll
    for (int i = 0; i < 8; ++i) {
        u16 hb = f2bf(xs[i]);
        hv[i] = (short)hb;
        lv[i] = (short)f2bf(xs[i] - bf2f(hb));
    }
    *(short8*)(hi + i8) = hv;
    *(short8*)(lo + i8) = lv;
}

// ---- prep: V [bh][k][d] fp32  ->  V^T hi/lo bf16 [bh][d][k] ----
__global__ void prep_vt(const float* __restrict__ V, u16* __restrict__ vthi,
                        u16* __restrict__ vtlo) {
    __shared__ float tile[64][65];
    const int bh = blockIdx.y;
    const int k0 = blockIdx.x * 64;
    const int t = threadIdx.x;
    {
        int r = t >> 2, c0 = (t & 3) * 16;
        const float* src = V + ((size_t)bh * S_LEN + k0 + r) * D_HEAD + c0;
        #pragma unroll
        for (int i = 0; i < 16; i += 4) {
            f32x4 v = *(const f32x4*)(src + i);
            tile[r][c0 + i + 0] = v[0];
            tile[r][c0 + i + 1] = v[1];
            tile[r][c0 + i + 2] = v[2];
            tile[r][c0 + i + 3] = v[3];
        }
    }
    __syncthreads();
    {
        int d = t >> 2, kc = (t & 3) * 16;
        size_t ob = ((size_t)bh * D_HEAD + d) * S_LEN + k0 + kc;
        #pragma unroll
        for (int half = 0; half < 2; ++half) {
            short8 hv, lv;
            #pragma unroll
            for (int i = 0; i < 8; ++i) {
                float x = tile[kc + half * 8 + i][d];
                u16 hb = f2bf(x);
                hv[i] = (short)hb;
                lv[i] = (short)f2bf(x - bf2f(hb));
            }
            *(short8*)(vthi + ob + half * 8) = hv;
            *(short8*)(vtlo + ob + half * 8) = lv;
        }
    }
}

// ============================================================================
// main: two-pass fused attention. 64 q/block, 8 waves (4 wq x 2 wk).
// LDS 80KB: buf[2][4 tiles][8KB] (Khi,Klo,Vhi,Vlo) + 16KB p-buffer (aliased:
// Q-staging, stats, out-reduce). All tiles XOR-swizzled: LDS[r][bb] holds
// global 16B-block (bb ^ (r&7)) of row r (swizzle applied on the gload_lds
// SOURCE address; LDS writes stay linear per m104/m173).
// ============================================================================
__launch_bounds__(512, 4)
__global__ void attn_main(const float* __restrict__ Q, const int* __restrict__ mask,
                          const float* __restrict__ bias_d,
                          const u16* __restrict__ khi_g, const u16* __restrict__ klo_g,
                          const u16* __restrict__ vhi_g, const u16* __restrict__ vlo_g,
                          float* __restrict__ outp, float* __restrict__ p_out) {
    __shared__ __align__(16) char smem[81920];
    u16* pball = (u16*)(smem + 65536);       // 16KB: per-wave p hi/lo; aliases Q-stage/stats/out-reduce

    const int tid = threadIdx.x;
    const int w = tid >> 6, l = tid & 63;
    const int wq = w & 3, wk = w >> 2;
    const int g = l >> 4, lq = l & 15;
    const int r7 = lq & 7;
    const int bid = blockIdx.x;
    const int bh = bid & 15, b = bh >> 2, h = bh & 3;   // bid%8 == bh%8 -> same-bh blocks share an XCD
    const int q0 = (bid >> 4) * 64;

    const float* Qp = Q + (size_t)bh * S_LEN * D_HEAD;
    const int* mp = mask + b * S_LEN;
    const u16* khp = khi_g + (size_t)bh * S_LEN * D_HEAD;
    const u16* klp = klo_g + (size_t)bh * S_LEN * D_HEAD;
    const u16* vhp = vhi_g + (size_t)bh * D_HEAD * S_LEN;
    const u16* vlp = vlo_g + (size_t)bh * D_HEAD * S_LEN;

    // ---- stage Q tile -> bf16 hi/lo, swizzle-written into pball region ----
    u16* qh = pball;             // [64][64] bf16
    u16* ql = pball + 4096;
    {
        int sr = tid >> 3, tb = tid & 7;
        const float* src = Qp + (size_t)(q0 + sr) * D_HEAD + tb * 8;
        f32x4 a = *(const f32x4*)src;
        f32x4 c = *(const f32x4*)(src + 4);
        float xs[8] = {a[0], a[1], a[2], a[3], c[0], c[1], c[2], c[3]};
        short8 hv, lv;
        #pragma unroll
        for (int i = 0; i < 8; ++i) {
            u16 hb = f2bf(xs[i]);
            hv[i] = (short)hb;
            lv[i] = (short)f2bf(xs[i] - bf2f(hb));
        }
        int dst = sr * 64 + ((tb ^ (sr & 7)) * 8);
        *(short8*)(qh + dst) = hv;
        *(short8*)(ql + dst) = lv;
    }
    // ---- pass-1 prologue: stage buf0 K-hi (chunk w per wave) ----
    {
        int r = w * 8 + (l >> 3), bb = l & 7, ub = bb ^ (r & 7);
        gl_lds16(khp + (size_t)r * 64 + ub * 8, smem + w * 1024);
    }
    __syncthreads();   // Q visible, buf0 K-hi landed (vmcnt drained)

    short8 qfh[2], qfl[2];   // B-frags: col=q(lane&15), k-dim=d
    const int qrow = 16 * wq + lq;
    #pragma unroll
    for (int c = 0; c < 2; ++c) {
        int blk = ((4 * c + g) ^ r7) * 8;
        qfh[c] = *(const short8*)(qh + qrow * 64 + blk);
        qfl[c] = *(const short8*)(ql + qrow * 64 + blk);
    }
    const int qq = q0 + qrow;
    const float* bprow = bias_d + h * 4096 + 2047 - qq;

    // ================= PASS 1: row stats (plain bf16 QK^T) =================
    float m = -INFINITY, lsum = 0.0f;
    for (int t = 0; t < 32; ++t) {
        const u16* kh = (const u16*)(smem + (t & 1) * 32768);
        if (t + 1 < 32) {   // stage next K-hi tile
            int r = w * 8 + (l >> 3), bb = l & 7, ub = bb ^ (r & 7);
            gl_lds16(khp + (size_t)((t + 1) * 64 + r) * 64 + ub * 8,
                     smem + ((t + 1) & 1) * 32768 + w * 1024);
        }
        #pragma unroll
        for (int t2 = 0; t2 < 2; ++t2) {
            const int krow = 32 * wk + 16 * t2 + lq;
            f32x4 acc = {0.f, 0.f, 0.f, 0.f};
            #pragma unroll
            for (int c = 0; c < 2; ++c) {
                short8 af = *(const short8*)(kh + krow * 64 + ((4 * c + g) ^ r7) * 8);
                acc = __builtin_amdgcn_mfma_f32_16x16x32_bf16(af, qfh[c], acc, 0, 0, 0);
            }
            const int k0 = t * 64 + 32 * wk + 16 * t2 + 4 * g;
            const int4 mv = *(const int4*)(mp + k0);
            float sv0 = mv.x ? fmaf(acc[0], 0.125f, bprow[k0 + 0]) : -1e9f;
            float sv1 = mv.y ? fmaf(acc[1], 0.125f, bprow[k0 + 1]) : -1e9f;
            float sv2 = mv.z ? fmaf(acc[2], 0.125f, bprow[k0 + 2]) : -1e9f;
            float sv3 = mv.w ? fmaf(acc[3], 0.125f, bprow[k0 + 3]) : -1e9f;
            float tmax = fmaxf(fmaxf(sv0, sv1), fmaxf(sv2, sv3));
            float mn = fmaxf(m, tmax);
            lsum = lsum * __expf(m - mn) + __expf(sv0 - mn) + __expf(sv1 - mn)
                 + __expf(sv2 - mn) + __expf(sv3 - mn);
            m = mn;
        }
        __syncthreads();
    }
    // combine the 4 k-slices held across lane groups (lanes ^16, ^32)
    #pragma unroll
    for (int off = 16; off <= 32; off <<= 1) {
        float mo = __shfl_xor(m, off);
        float lo2 = __shfl_xor(lsum, off);
        float mn = fmaxf(m, mo);
        lsum = lsum * __expf(m - mn) + lo2 * __expf(mo - mn);
        m = mn;
    }
    float* stats = (float*)pball;   // [4][64] partials (Q frags already consumed)
    if (g == 0) {
        stats[(wk * 2 + 0) * 64 + qrow] = m;
        stats[(wk * 2 + 1) * 64 + qrow] = lsum;
    }
    // ---- pass-2 prologue: stage buf0 all 4 tiles (4 chunks per wave) ----
    {
        int rr = l >> 3, bb = l & 7;
        #pragma unroll
        for (int j = 0; j < 4; ++j) {
            int idx = 4 * w + j, T = idx >> 3, ch = idx & 7;
            int r = ch * 8 + rr, ub = bb ^ (r & 7);
            const u16* src;
            if (T == 0)      src = khp + (size_t)r * 64 + ub * 8;
            else if (T == 1) src = klp + (size_t)r * 64 + ub * 8;
            else if (T == 2) src = vhp + (size_t)r * 2048 + ub * 8;
            else             src = vlp + (size_t)r * 2048 + ub * 8;
            gl_lds16(src, smem + T * 8192 + ch * 1024);
        }
    }
    __syncthreads();   // stats visible, buf0 staged
    float m0 = stats[qrow], l0 = stats[64 + qrow];
    float m1 = stats[128 + qrow], l1 = stats[192 + qrow];
    const float mq = fmaxf(m0, m1);
    const float rlq = 1.0f / (l0 * __expf(m0 - mq) + l1 * __expf(m1 - mq));
    __syncthreads();   // protect stats reads before p-buffer writes

    // ================= PASS 2: exact scores (bf16x3), write p, accumulate PV =================
    f32x4 acco[4] = {{0.f,0.f,0.f,0.f},{0.f,0.f,0.f,0.f},{0.f,0.f,0.f,0.f},{0.f,0.f,0.f,0.f}};
    u16* pbh = pball + w * 1024;
    u16* pbl = pbh + 512;
    float* po_row = p_out + (size_t)bh * S_LEN * S_LEN + (size_t)qq * S_LEN;

    for (int t = 0; t < 32; ++t) {
        const int cb = (t & 1) * 32768;
        const u16* kh = (const u16*)(smem + cb);
        const u16* kl = (const u16*)(smem + cb + 8192);
        const u16* vh = (const u16*)(smem + cb + 16384);
        const u16* vl = (const u16*)(smem + cb + 24576);
        if (t + 1 < 32) {   // stage next 4 tiles
            const int nb = ((t + 1) & 1) * 32768;
            const size_t kbn = (size_t)(t + 1) * 64;
            int rr = l >> 3, bb = l & 7;
            #pragma unroll
            for (int j = 0; j < 4; ++j) {
                int idx = 4 * w + j, T = idx >> 3, ch = idx & 7;
                int r = ch * 8 + rr, ub = bb ^ (r & 7);
                const u16* src;
                if (T == 0)      src = khp + (kbn + r) * 64 + ub * 8;
                else if (T == 1) src = klp + (kbn + r) * 64 + ub * 8;
                else if (T == 2) src = vhp + (size_t)r * 2048 + kbn + ub * 8;
                else             src = vlp + (size_t)r * 2048 + kbn + ub * 8;
                gl_lds16(src, smem + nb + T * 8192 + ch * 1024);
            }
        }
        const int kb = t * 64;
        #pragma unroll
        for (int t2 = 0; t2 < 2; ++t2) {
            const int krow = 32 * wk + 16 * t2 + lq;
            f32x4 acc = {0.f, 0.f, 0.f, 0.f};
            #pragma unroll
            for (int c = 0; c < 2; ++c) {
                int blk = ((4 * c + g) ^ r7) * 8;
                short8 ah = *(const short8*)(kh + krow * 64 + blk);
                short8 al = *(const short8*)(kl + krow * 64 + blk);
                acc = __builtin_amdgcn_mfma_f32_16x16x32_bf16(ah, qfh[c], acc, 0, 0, 0);
                acc = __builtin_amdgcn_mfma_f32_16x16x32_bf16(al, qfh[c], acc, 0, 0, 0);
                acc = __builtin_amdgcn_mfma_f32_16x16x32_bf16(ah, qfl[c], acc, 0, 0, 0);
            }
            const int k0 = kb + 32 * wk + 16 * t2 + 4 * g;
            const int4 mv = *(const int4*)(mp + k0);
            float s0 = mv.x ? fmaf(acc[0], 0.125f, bprow[k0 + 0]) : -1e9f;
            float s1 = mv.y ? fmaf(acc[1], 0.125f, bprow[k0 + 1]) : -1e9f;
            float s2 = mv.z ? fmaf(acc[2], 0.125f, bprow[k0 + 2]) : -1e9f;
            float s3 = mv.w ? fmaf(acc[3], 0.125f, bprow[k0 + 3]) : -1e9f;
            float p0 = __expf(s0 - mq) * rlq;
            float p1 = __expf(s1 - mq) * rlq;
            float p2 = __expf(s2 - mq) * rlq;
            float p3 = __expf(s3 - mq) * rlq;
            f32x4 pw = {p0, p1, p2, p3};
            __builtin_nontemporal_store(pw, (f32x4*)(po_row + k0));   // streaming, keep L2 for K/V
            short4v ph4, pl4;
            float pv[4] = {p0, p1, p2, p3};
            #pragma unroll
            for (int r = 0; r < 4; ++r) {
                u16 hb = f2bf(pv[r]);
                ph4[r] = (short)hb;
                pl4[r] = (short)f2bf(pv[r] - bf2f(hb));
            }
            *(short4v*)(pbh + (lq << 5) + 16 * t2 + 4 * g) = ph4;
            *(short4v*)(pbl + (lq << 5) + 16 * t2 + 4 * g) = pl4;
        }
        // PV: A = P[16q x 32k] (own wave's LDS buffer), B = V^T[d][k]
        const short8 pfh = *(const short8*)(pbh + (lq << 5) + 8 * g);
        const short8 pfl = *(const short8*)(pbl + (lq << 5) + 8 * g);
        #pragma unroll
        for (int n = 0; n < 4; ++n) {
            int blk = ((4 * wk + g) ^ r7) * 8;
            const short8 bhf = *(const short8*)(vh + (16 * n + lq) * 64 + blk);
            const short8 blf = *(const short8*)(vl + (16 * n + lq) * 64 + blk);
            acco[n] = __builtin_amdgcn_mfma_f32_16x16x32_bf16(pfh, bhf, acco[n], 0, 0, 0);
            acco[n] = __builtin_amdgcn_mfma_f32_16x16x32_bf16(pfl, bhf, acco[n], 0, 0, 0);
            acco[n] = __builtin_amdgcn_mfma_f32_16x16x32_bf16(pfh, blf, acco[n], 0, 0, 0);
        }
        __syncthreads();
    }

    // ---- reduce the two k-half waves and store out ----
    float* ored = (float*)pball;    // [64 q][64 d]
    if (wk == 1) {
        #pragma unroll
        for (int n = 0; n < 4; ++n)
            #pragma unroll
            for (int r = 0; r < 4; ++r)
                ored[(wq * 16 + 4 * g + r) * 64 + 16 * n + lq] = acco[n][r];
    }
    __syncthreads();
    if (wk == 0) {
        #pragma unroll
        for (int n = 0; n < 4; ++n) {
            #pragma unroll
            for (int r = 0; r < 4; ++r) {
                float v = acco[n][r] + ored[(wq * 16 + 4 * g + r) * 64 + 16 * n + lq];
                outp[((size_t)bh * S_LEN + q0 + 16 * wq + 4 * g + r) * D_HEAD + 16 * n + lq] = v;
            }
        }
    }
}

extern "C" void kernel_launch(void* const* d_in, const int* in_sizes, int n_in,
                              void* d_out, int out_size, void* d_ws, size_t ws_size,
                              hipStream_t stream) {
    const float* Q = (const float*)d_in[0];
    const float* K = (const float*)d_in[1];
    const float* V = (const float*)d_in[2];
    const int* mask = (const int*)d_in[3];
    const float* table = (const float*)d_in[4];

    float* outp = (float*)d_out;
    float* p_out = outp + (size_t)4 * 4 * 2048 * 64;   // out first, then p_attn

    float* bias_d = (float*)d_ws;                                   // 64 KB
    u16* khi = (u16*)((char*)d_ws + 65536);                         // 4 MB each
    u16* klo = khi + (size_t)16 * S_LEN * D_HEAD;
    u16* vthi = klo + (size_t)16 * S_LEN * D_HEAD;
    u16* vtlo = vthi + (size_t)16 * S_LEN * D_HEAD;

    prep_bias<<<16, 256, 0, stream>>>(table, bias_d);
    prep_split<<<1024, 256, 0, stream>>>(K, khi, klo);
    prep_vt<<<dim3(32, 16), 256, 0, stream>>>(V, vthi, vtlo);
    attn_main<<<512, 512, 0, stream>>>(Q, mask, bias_d, khi, klo, vthi, vtlo, outp, p_out);
}

// Round 3
// 167.513 us; speedup vs baseline: 1.1765x; 1.0329x over previous
//
#include <hip/hip_runtime.h>
#include <hip/hip_bf16.h>
#include <math.h>

typedef __attribute__((ext_vector_type(8))) short short8;
typedef __attribute__((ext_vector_type(4))) short short4v;
typedef __attribute__((ext_vector_type(4))) float f32x4;
typedef unsigned short u16;

#define S_LEN 2048
#define D_HEAD 64
#define C2 0.18033688011112043f   /* log2(e)/8 */

static __device__ __forceinline__ u16 f2bf(float x) {
    union { float f; unsigned u; } a; a.f = x;
    unsigned r = a.u + (0x7fffu + ((a.u >> 16) & 1u));   // RNE
    return (u16)(r >> 16);
}
static __device__ __forceinline__ float bf2f(u16 h) {
    union { unsigned u; float f; } a; a.u = ((unsigned)h) << 16;
    return a.f;
}
static __device__ __forceinline__ u16 bfbits(float x) {
    __hip_bfloat16 h = __float2bfloat16(x);              // RNE, compiler-friendly (m240)
    return __builtin_bit_cast(unsigned short, h);
}
static __device__ __forceinline__ float exp2v(float x) { // v_exp_f32 = 2^x, 1 inst
    float r; asm("v_exp_f32 %0, %1" : "=v"(r) : "v"(x)); return r;
}

static __device__ __forceinline__ void gl_lds16(const void* g, void* l) {
    __builtin_amdgcn_global_load_lds(
        (const __attribute__((address_space(1))) unsigned int*)g,
        (__attribute__((address_space(3))) unsigned int*)l, 16, 0, 0);
}

// ---- prep: T5 bias baked to [h][delta+2047], pre-scaled by log2(e)/8 ----
__global__ void prep_bias(const float* __restrict__ table, float* __restrict__ bias_d) {
    int idx = blockIdx.x * blockDim.x + threadIdx.x;   // 0..4095
    if (idx >= 4096) return;
    int delta = idx - 2047;                 // k - q
    int bpos = (delta > 0) ? 16 : 0;
    int ad = delta < 0 ? -delta : delta;
    int rel;
    if (ad < 8) {
        rel = bpos + ad;
    } else {
        float rp = (float)ad;
        int lg = 8 + (int)(logf(rp / 8.0f) / 2.772588722239781f * 8.0f);  // log(16)
        if (lg > 15) lg = 15;
        rel = bpos + lg;
    }
    #pragma unroll
    for (int h = 0; h < 4; ++h)
        bias_d[h * 4096 + idx] = C2 * table[rel * 4 + h];
}

// ---- prep: elementwise fp32 -> bf16 hi/lo split (for K) ----
__global__ void prep_split(const float* __restrict__ src, u16* __restrict__ hi,
                           u16* __restrict__ lo) {
    size_t i8 = ((size_t)blockIdx.x * 256 + threadIdx.x) * 8;
    f32x4 a = *(const f32x4*)(src + i8);
    f32x4 b = *(const f32x4*)(src + i8 + 4);
    float xs[8] = {a[0], a[1], a[2], a[3], b[0], b[1], b[2], b[3]};
    short8 hv, lv;
    #pragma unroll
    for (int i = 0; i < 8; ++i) {
        u16 hb = f2bf(xs[i]);
        hv[i] = (short)hb;
        lv[i] = (short)f2bf(xs[i] - bf2f(hb));
    }
    *(short8*)(hi + i8) = hv;
    *(short8*)(lo + i8) = lv;
}

// ---- prep: V [bh][k][d] fp32  ->  V^T hi/lo bf16 [bh][d][k] ----
__global__ void prep_vt(const float* __restrict__ V, u16* __restrict__ vthi,
                        u16* __restrict__ vtlo) {
    __shared__ float tile[64][65];
    const int bh = blockIdx.y;
    const int k0 = blockIdx.x * 64;
    const int t = threadIdx.x;
    {
        int r = t >> 2, c0 = (t & 3) * 16;
        const float* src = V + ((size_t)bh * S_LEN + k0 + r) * D_HEAD + c0;
        #pragma unroll
        for (int i = 0; i < 16; i += 4) {
            f32x4 v = *(const f32x4*)(src + i);
            tile[r][c0 + i + 0] = v[0];
            tile[r][c0 + i + 1] = v[1];
            tile[r][c0 + i + 2] = v[2];
            tile[r][c0 + i + 3] = v[3];
        }
    }
    __syncthreads();
    {
        int d = t >> 2, kc = (t & 3) * 16;
        size_t ob = ((size_t)bh * D_HEAD + d) * S_LEN + k0 + kc;
        #pragma unroll
        for (int half = 0; half < 2; ++half) {
            short8 hv, lv;
            #pragma unroll
            for (int i = 0; i < 8; ++i) {
                float x = tile[kc + half * 8 + i][d];
                u16 hb = f2bf(x);
                hv[i] = (short)hb;
                lv[i] = (short)f2bf(x - bf2f(hb));
            }
            *(short8*)(vthi + ob + half * 8) = hv;
            *(short8*)(vtlo + ob + half * 8) = lv;
        }
    }
}

// ============================================================================
// main: two-pass fused attention, log2-domain max-free softmax.
// 64 q/block, 8 waves (4 wq x 2 wk). LDS 74KB:
//   [0..64K)   stage area. pass1: Khi128 dbuf 2x16KB (+Q hi/lo at 32K..48K,
//              stats 512B at 32K after pass1). pass2: dbuf 2x32KB
//              {Khi,Klo,Vh,Vl} x 8KB. epilogue: out-reduce 16KB at 0.
//   [64K..74K) per-wave p-hi buffer, 16 rows x 40 u16 (stride-40 kills the
//              8-way write conflict; reads stay 16B-aligned minimum-time).
// Tiles XOR-swizzled via pre-swizzled GLOBAL source addrs (rule #21),
// LDS dests linear (gl_lds requirement).
// ============================================================================
__launch_bounds__(512, 4)
__global__ void attn_main(const float* __restrict__ Q, const int* __restrict__ mask,
                          const float* __restrict__ bias2,
                          const u16* __restrict__ khi_g, const u16* __restrict__ klo_g,
                          const u16* __restrict__ vhi_g, const u16* __restrict__ vlo_g,
                          float* __restrict__ outp, float* __restrict__ p_out) {
    __shared__ __align__(16) char smem[75776];

    const int tid = threadIdx.x;
    const int w = tid >> 6, l = tid & 63;
    const int wq = w & 3, wk = w >> 2;
    const int g = l >> 4, lq = l & 15;
    const int r7 = lq & 7;
    const int bid = blockIdx.x;
    const int bh = bid & 15, b = bh >> 2, h = bh & 3;   // bid%8 == bh%8: bh pinned per XCD
    const int q0 = (bid >> 4) * 64;

    const float* Qp = Q + (size_t)bh * (S_LEN * D_HEAD);
    const int* mp = mask + b * S_LEN;
    const u16* khp = khi_g + (size_t)bh * (S_LEN * D_HEAD);
    const u16* klp = klo_g + (size_t)bh * (S_LEN * D_HEAD);
    const u16* vhp = vhi_g + (size_t)bh * (S_LEN * D_HEAD);
    const u16* vlp = vlo_g + (size_t)bh * (S_LEN * D_HEAD);

    // ---- stage Q -> bf16 hi/lo (swizzled ds_write) at smem+32K ----
    u16* qh = (u16*)(smem + 32768);
    u16* ql = (u16*)(smem + 40960);
    {
        int sr = tid >> 3, tb = tid & 7;
        const float* src = Qp + (size_t)(q0 + sr) * D_HEAD + tb * 8;
        f32x4 a = *(const f32x4*)src;
        f32x4 c = *(const f32x4*)(src + 4);
        float xs[8] = {a[0], a[1], a[2], a[3], c[0], c[1], c[2], c[3]};
        short8 hv, lv;
        #pragma unroll
        for (int i = 0; i < 8; ++i) {
            u16 hb = f2bf(xs[i]);
            hv[i] = (short)hb;
            lv[i] = (short)f2bf(xs[i] - bf2f(hb));
        }
        int dst = sr * 64 + ((tb ^ (sr & 7)) * 8);
        *(short8*)(qh + dst) = hv;
        *(short8*)(ql + dst) = lv;
    }

    // hoisted staging geometry (shared by both passes)
    const int rr3 = tid >> 3;                       // chunk row 0..63
    const int ub0 = (((tid & 7) ^ (rr3 & 7)) * 8);  // swizzled 8-elem block
    // pass-1 prologue: stage K-hi rows 0..127 -> smem+0 (16KB)
    const u16* s1a = khp + (size_t)rr3 * 64 + ub0;
    const u16* s1b = s1a + 4096;                    // rows 64..127 ((64+r)&7==r&7)
    gl_lds16(s1a, smem + tid * 16);
    gl_lds16(s1b, smem + 8192 + tid * 16);
    __syncthreads();

    short8 qfh[2], qfl[2];
    const int qrow = 16 * wq + lq;
    #pragma unroll
    for (int c = 0; c < 2; ++c) {
        int blk = ((4 * c + g) ^ r7) * 8;
        qfh[c] = *(const short8*)(qh + qrow * 64 + blk);
        qfl[c] = *(const short8*)(ql + qrow * 64 + blk);
    }
    const int qq = q0 + qrow;

    // ================= PASS 1: l = sum(2^s2), K-tile 128, 16 iters =================
    const int* mP1 = mp + 64 * wk + 4 * g;
    const float* bP1 = bias2 + h * 4096 + 2047 - qq + 64 * wk + 4 * g;
    float lsum = 0.0f;
    for (int t = 0; t < 16; ++t) {
        const u16* kh = (const u16*)(smem + (t & 1) * 16384);
        if (t < 15) {
            s1a += 8192; s1b += 8192;
            char* nb = smem + ((t + 1) & 1) * 16384 + tid * 16;
            gl_lds16(s1a, nb);
            gl_lds16(s1b, nb + 8192);
        }
        #pragma unroll
        for (int t2 = 0; t2 < 4; ++t2) {
            const int krow = 64 * wk + 16 * t2 + lq;
            f32x4 acc = {0.f, 0.f, 0.f, 0.f};
            #pragma unroll
            for (int c = 0; c < 2; ++c) {
                short8 af = *(const short8*)(kh + krow * 64 + ((4 * c + g) ^ r7) * 8);
                acc = __builtin_amdgcn_mfma_f32_16x16x32_bf16(af, qfh[c], acc, 0, 0, 0);
            }
            const int4 mv = *(const int4*)(mP1 + 16 * t2);
            float s0 = mv.x ? fmaf(acc[0], C2, bP1[16 * t2 + 0]) : -1e9f;
            float s1 = mv.y ? fmaf(acc[1], C2, bP1[16 * t2 + 1]) : -1e9f;
            float s2 = mv.z ? fmaf(acc[2], C2, bP1[16 * t2 + 2]) : -1e9f;
            float s3 = mv.w ? fmaf(acc[3], C2, bP1[16 * t2 + 3]) : -1e9f;
            lsum += exp2v(s0) + exp2v(s1) + exp2v(s2) + exp2v(s3);
        }
        mP1 += 128; bP1 += 128;
        __syncthreads();
    }
    lsum += __shfl_xor(lsum, 16);
    lsum += __shfl_xor(lsum, 32);
    float* stats = (float*)(smem + 32768);   // Q area dead (frags in regs)
    if (g == 0) stats[wk * 64 + qrow] = lsum;

    // ---- pass-2 staging pointers + prologue (buf0: Khi,Klo,Vh,Vl) ----
    const u16* sKh = khp + (size_t)rr3 * 64 + ub0;
    const u16* sKl = klp + (size_t)rr3 * 64 + ub0;
    const u16* sVh = vhp + (size_t)rr3 * 2048 + ub0;
    const u16* sVl = vlp + (size_t)rr3 * 2048 + ub0;
    {
        char* d0 = smem + tid * 16;
        gl_lds16(sKh, d0);
        gl_lds16(sKl, d0 + 8192);
        gl_lds16(sVh, d0 + 16384);
        gl_lds16(sVl, d0 + 24576);
    }
    __syncthreads();   // stats visible + buf0 staged (vmcnt drained)
    float lr2q;
    {
        float L = stats[qrow] + stats[64 + qrow];
        float lg; asm("v_log_f32 %0, %1" : "=v"(lg) : "v"(L));
        lr2q = -lg;    // p = 2^(s2 + lr2q)
    }

    // ================= PASS 2: p = 2^(s2+lr2), write p, PV (P-hi x V-hi/lo) =================
    f32x4 acco[4] = {{0.f,0.f,0.f,0.f},{0.f,0.f,0.f,0.f},{0.f,0.f,0.f,0.f},{0.f,0.f,0.f,0.f}};
    u16* pbh = (u16*)(smem + 65536) + w * 640;            // stride-40 rows
    const int* mP = mp + 32 * wk + 4 * g;
    const float* bP = bias2 + h * 4096 + 2047 - qq + 32 * wk + 4 * g;
    float* pP = p_out + (size_t)bh * (S_LEN * S_LEN) + (size_t)qq * S_LEN + 32 * wk + 4 * g;
    const int kAoff0 = (32 * wk + lq) * 128;              // K frag byte base (+t2*2048)
    const int voffb = lq * 128 + ((4 * wk + g) ^ r7) * 16; // V frag byte base (+n*2048)
    u16* pwr = pbh + lq * 40 + g * 4;                     // p write (+t2*16)
    const u16* prd = pbh + lq * 40 + g * 8;               // p frag read

    for (int t = 0; t < 32; ++t) {
        const int cb = (t & 1) * 32768;
        if (t < 31) {
            sKh += 4096; sKl += 4096; sVh += 64; sVl += 64;
            char* d0 = smem + ((t + 1) & 1) * 32768 + tid * 16;
            gl_lds16(sKh, d0);
            gl_lds16(sKl, d0 + 8192);
            gl_lds16(sVh, d0 + 16384);
            gl_lds16(sVl, d0 + 24576);
        }
        #pragma unroll
        for (int t2 = 0; t2 < 2; ++t2) {
            const char* kbase = smem + cb + kAoff0 + t2 * 2048;
            f32x4 acc = {0.f, 0.f, 0.f, 0.f};
            #pragma unroll
            for (int c = 0; c < 2; ++c) {
                int blk = ((4 * c + g) ^ r7) * 16;
                short8 ah = *(const short8*)(kbase + blk);
                short8 al = *(const short8*)(kbase + 8192 + blk);
                acc = __builtin_amdgcn_mfma_f32_16x16x32_bf16(ah, qfh[c], acc, 0, 0, 0);
                acc = __builtin_amdgcn_mfma_f32_16x16x32_bf16(al, qfh[c], acc, 0, 0, 0);
                acc = __builtin_amdgcn_mfma_f32_16x16x32_bf16(ah, qfl[c], acc, 0, 0, 0);
            }
            const int4 mv = *(const int4*)(mP + 16 * t2);
            float p0 = exp2v(mv.x ? fmaf(acc[0], C2, bP[16 * t2 + 0]) + lr2q : -1e9f);
            float p1 = exp2v(mv.y ? fmaf(acc[1], C2, bP[16 * t2 + 1]) + lr2q : -1e9f);
            float p2 = exp2v(mv.z ? fmaf(acc[2], C2, bP[16 * t2 + 2]) + lr2q : -1e9f);
            float p3 = exp2v(mv.w ? fmaf(acc[3], C2, bP[16 * t2 + 3]) + lr2q : -1e9f);
            f32x4 pw = {p0, p1, p2, p3};
            __builtin_nontemporal_store(pw, (f32x4*)(pP + 16 * t2));
            short4v ph4;
            ph4[0] = (short)bfbits(p0);
            ph4[1] = (short)bfbits(p1);
            ph4[2] = (short)bfbits(p2);
            ph4[3] = (short)bfbits(p3);
            *(short4v*)(pwr + 16 * t2) = ph4;
        }
        // PV: A = P-hi [16q x 32k] (own wave), B = V^T hi/lo
        const short8 pf = *(const short8*)prd;
        #pragma unroll
        for (int n = 0; n < 4; ++n) {
            const char* vb = smem + cb + 16384 + voffb + n * 2048;
            short8 bhf = *(const short8*)vb;
            short8 blf = *(const short8*)(vb + 8192);
            acco[n] = __builtin_amdgcn_mfma_f32_16x16x32_bf16(pf, bhf, acco[n], 0, 0, 0);
            acco[n] = __builtin_amdgcn_mfma_f32_16x16x32_bf16(pf, blf, acco[n], 0, 0, 0);
        }
        mP += 64; bP += 64; pP += 64;
        __syncthreads();
    }

    // ---- reduce the two wk halves (stage area is dead) and store out ----
    float* ored = (float*)smem;    // [64 q][64 d]
    if (wk == 1) {
        #pragma unroll
        for (int n = 0; n < 4; ++n)
            #pragma unroll
            for (int r = 0; r < 4; ++r)
                ored[(wq * 16 + 4 * g + r) * 64 + 16 * n + lq] = acco[n][r];
    }
    __syncthreads();
    if (wk == 0) {
        #pragma unroll
        for (int n = 0; n < 4; ++n) {
            #pragma unroll
            for (int r = 0; r < 4; ++r) {
                float v = acco[n][r] + ored[(wq * 16 + 4 * g + r) * 64 + 16 * n + lq];
                outp[((size_t)bh * S_LEN + q0 + 16 * wq + 4 * g + r) * D_HEAD + 16 * n + lq] = v;
            }
        }
    }
}

extern "C" void kernel_launch(void* const* d_in, const int* in_sizes, int n_in,
                              void* d_out, int out_size, void* d_ws, size_t ws_size,
                              hipStream_t stream) {
    const float* Q = (const float*)d_in[0];
    const float* K = (const float*)d_in[1];
    const float* V = (const float*)d_in[2];
    const int* mask = (const int*)d_in[3];
    const float* table = (const float*)d_in[4];

    float* outp = (float*)d_out;
    float* p_out = outp + (size_t)4 * 4 * 2048 * 64;   // out first, then p_attn

    float* bias_d = (float*)d_ws;                                   // 64 KB
    u16* khi = (u16*)((char*)d_ws + 65536);                         // 4 MB each
    u16* klo = khi + (size_t)16 * S_LEN * D_HEAD;
    u16* vthi = klo + (size_t)16 * S_LEN * D_HEAD;
    u16* vtlo = vthi + (size_t)16 * S_LEN * D_HEAD;

    prep_bias<<<16, 256, 0, stream>>>(table, bias_d);
    prep_split<<<1024, 256, 0, stream>>>(K, khi, klo);
    prep_vt<<<dim3(32, 16), 256, 0, stream>>>(V, vthi, vtlo);
    attn_main<<<512, 512, 0, stream>>>(Q, mask, bias_d, khi, klo, vthi, vtlo, outp, p_out);
}